// Round 8
// baseline (441.986 us; speedup 1.0000x reference)
//
#include <hip/hip_runtime.h>

#define IMGS 96
#define HW   262144      // 512*512
#define NPTS 12288       // 96*128
#define OOBV 1e-5f

// ws layout (float offsets)
static constexpr size_t PYR_OFF   = 0;        // 8,388,576 floats (levels 1..9, packed)
static constexpr size_t PFIN_OFF  = 8388576;  // 24576 floats (final p)
static constexpr size_t PLMAX_OFF = 8413152;  // 11 floats (plmax[0..10])
static constexpr size_t CNT_OFF   = 8413163;  // 1 int
static constexpr size_t LIST_OFF  = 8413164;  // 12288 ints

__device__ __forceinline__ int clampi(int v, int lo, int hi) {
    v = v < lo ? lo : v;
    return v > hi ? hi : v;
}

// ---- masks_out scatter + dedup'd owner list of set pixels ----
__global__ void k_scatter(const float* __restrict__ pts, float* __restrict__ mo,
                          int* __restrict__ cnt, int* __restrict__ plist) {
    int i = blockIdx.x * blockDim.x + threadIdx.x;
    if (i >= NPTS) return;
    float px = pts[2*i], py = pts[2*i+1];
    int xi = clampi((int)rintf(px), 0, 511);
    int yi = clampi((int)rintf(py), 0, 511);
    int gp = (i >> 7) * HW + yi * 512 + xi;
    float old = atomicExch(&mo[gp], 1.0f);
    if (old == 0.0f) {                 // first claimer owns this pixel
        int k = atomicAdd(cnt, 1);
        plist[k] = gp;
    }
}

// ---- level 1 (256^2) from -masks_target only (0.01*mo added as correction) ----
__global__ void k_lvl1(const float* __restrict__ mt, float* __restrict__ out) {
    int t = blockIdx.x * blockDim.x + threadIdx.x;
    if (t >= IMGS * 65536) return;
    int j = t & 255, i = (t >> 8) & 255, img = t >> 16;
    const float* m = mt + (size_t)img * HW;
    float s = 0.0f;
    #pragma unroll
    for (int dy = -1; dy <= 1; ++dy) {
        int y = 2*i + dy;
        #pragma unroll
        for (int dx = -1; dx <= 1; ++dx) {
            int x = 2*j + dx;
            s += (y >= 0 && y < 512 && x >= 0 && x < 512) ? -m[y*512 + x] : OOBV;
        }
    }
    out[t] = s / 9.0f;
}

// ---- sparse correction: each set pixel adds 0.01/9 to covering lvl1 cells ----
__global__ void k_corr1(const int* __restrict__ cnt, const int* __restrict__ plist,
                        float* __restrict__ lvl1) {
    int k = blockIdx.x * blockDim.x + threadIdx.x;
    if (k >= *cnt) return;
    int gp = plist[k];
    int img = gp >> 18;
    int r = gp & (HW - 1);
    int y = r >> 9, x = r & 511;
    float* L = lvl1 + (size_t)img * 65536;
    const float c = 0.01f / 9.0f;
    int ilo = y >> 1, ihi = ((y + 1) >> 1) > 255 ? 255 : ((y + 1) >> 1);
    int jlo = x >> 1, jhi = ((x + 1) >> 1) > 255 ? 255 : ((x + 1) >> 1);
    for (int i = ilo; i <= ihi; ++i)
        for (int j = jlo; j <= jhi; ++j)
            atomicAdd(&L[i*256 + j], c);
}

// ---- level 2 (128^2) from level 1 (256^2) ----
__global__ void k_lvl2(const float* __restrict__ in, float* __restrict__ out) {
    int t = blockIdx.x * blockDim.x + threadIdx.x;
    if (t >= IMGS * 16384) return;
    int j = t & 127, i = (t >> 7) & 127, img = t >> 14;
    const float* m = in + (size_t)img * 65536;
    float s = 0.0f;
    #pragma unroll
    for (int dy = -1; dy <= 1; ++dy) {
        int y = 2*i + dy;
        #pragma unroll
        for (int dx = -1; dx <= 1; ++dx) {
            int x = 2*j + dx;
            s += (y >= 0 && y < 256 && x >= 0 && x < 256) ? m[y*256 + x] : OOBV;
        }
    }
    out[t] = s / 9.0f;
}

// ---- levels 3..9 fused, one block per image, LDS resident ----
__global__ __launch_bounds__(256) void k_pyrtail(float* __restrict__ pyr) {
    __shared__ float buf[5461];   // 64^2 + 32^2 + 16^2 + 8^2 + 4^2 + 2^2 + 1
    int img = blockIdx.x;
    const float* L2 = pyr + 6291456 + (size_t)img * 16384;   // lvl2
    // level 3 (64^2) from global lvl2 (128^2)
    for (int t = threadIdx.x; t < 4096; t += 256) {
        int i = t >> 6, j = t & 63;
        float s = 0.0f;
        #pragma unroll
        for (int dy = -1; dy <= 1; ++dy) {
            int y = 2*i + dy;
            #pragma unroll
            for (int dx = -1; dx <= 1; ++dx) {
                int x = 2*j + dx;
                s += (y >= 0 && y < 128 && x >= 0 && x < 128) ? L2[y*128 + x] : OOBV;
            }
        }
        float v = s / 9.0f;
        buf[t] = v;
        pyr[7864320 + (size_t)img * 4096 + t] = v;
    }
    __syncthreads();
    // levels 4..9 from LDS
    int inOff = 0, sin = 64;
    size_t goff = 8257536;
    while (sin > 1) {
        int sout = sin >> 1;
        int outOff = inOff + sin * sin;
        for (int t = threadIdx.x; t < sout * sout; t += 256) {
            int i = t / sout, j = t - i * sout;
            float s = 0.0f;
            for (int dy = -1; dy <= 1; ++dy) {
                int y = 2*i + dy;
                for (int dx = -1; dx <= 1; ++dx) {
                    int x = 2*j + dx;
                    s += (y >= 0 && y < sin && x >= 0 && x < sin) ? buf[inOff + y*sin + x] : OOBV;
                }
            }
            float v = s / 9.0f;
            buf[outOff + t] = v;
            pyr[goff + (size_t)img * sout * sout + t] = v;
        }
        __syncthreads();
        inOff = outOff; sin = sout;
        goff += (size_t)96 * sout * sout;
    }
}

// ---- on-the-fly ga at one pixel: bit-identical to the old dense k_ga ----
// vertical lerp then horizontal lerp per level, acc/10, then the sparse
// 0.01*masks_out correction keyed off mo[idx] (1.0 exactly once per set pixel).
__device__ __forceinline__ float ga_eval(const float* __restrict__ mt,
                                         const float* __restrict__ mo,
                                         const float* __restrict__ pyr,
                                         int img, int y, int x) {
    int idx = img * HW + y * 512 + x;
    float acc = -mt[idx];                      // grad0
    #pragma unroll
    for (int l = 0; l < 9; ++l) {
        const int s = 256 >> l;
        const float scale = (float)s * (1.0f / 512.0f);
        const float* Lp = pyr + (8388608 - (8388608 >> (2*l))) + (size_t)img * s * s;
        float fy = ((float)y + 0.5f) * scale - 0.5f;
        fy = fminf(fmaxf(fy, 0.0f), (float)(s - 1));   // edge clamp
        float fyf = floorf(fy);
        int y0 = (int)fyf;
        float ty = fy - fyf;
        int yb = (y0 + 1 < s) ? y0 + 1 : s - 1;
        float fx = ((float)x + 0.5f) * scale - 0.5f;
        fx = fminf(fmaxf(fx, 0.0f), (float)(s - 1));
        float fxf = floorf(fx);
        int x0 = (int)fxf;
        float tx = fx - fxf;
        int xb = (x0 + 1 < s) ? x0 + 1 : s - 1;        // pad-dup of last col
        float a = (1.0f - ty) * Lp[y0*s + x0] + ty * Lp[yb*s + x0];
        float b = (1.0f - ty) * Lp[y0*s + xb] + ty * Lp[yb*s + xb];
        acc += (1.0f - tx) * a + tx * b;
    }
    float v = acc / 10.0f;
    if (mo[idx] == 1.0f) v += 0.001f;          // dedup'd sparse correction
    return v;
}

// ---- speculative full trajectory: 10 steps, no grid sync, ga on the fly ----
// Gate has latch semantics: trajectories agree with reference up to the first
// t where plmax[t] <= 0.1; k_final truncates if that ever happens.
__global__ __launch_bounds__(256) void k_traj(const float* __restrict__ pts,
                                              const float* __restrict__ mt,
                                              const float* __restrict__ mo,
                                              const float* __restrict__ pyr,
                                              float* __restrict__ pfin,
                                              float* __restrict__ plmax) {
    int i = blockIdx.x * 256 + threadIdx.x;    // grid exactly 48x256 = NPTS
    float px = pts[2*i], py = pts[2*i+1];
    int img = i >> 7, n = i & 127;
    const float* M = mt + (size_t)img * HW;
    float d = expf(-(float)n * 0.078125f);     // exp(-n/128*10)
    float s0 = 0.0f, s1 = 0.0f;

    for (int t = 0; t < 10; ++t) {
        int xi = clampi((int)rintf(px), 0, 511);
        int yi = clampi((int)rintf(py), 0, 511);
        float pl = (1.0f - M[yi*512 + xi]) * d;
        // wave-level max reduce, one atomic per wave per step
        float r = pl;
        #pragma unroll
        for (int off = 32; off; off >>= 1) r = fmaxf(r, __shfl_xor(r, off, 64));
        if ((threadIdx.x & 63) == 0)
            atomicMax((int*)&plmax[t], __float_as_int(r));  // pl>=0 => bit order ok
        float gxp = (ga_eval(mt, mo, pyr, img, clampi(yi-1,0,511), xi)
                   - ga_eval(mt, mo, pyr, img, clampi(yi+1,0,511), xi)) * 0.5f;
        float gyp = (ga_eval(mt, mo, pyr, img, yi, clampi(xi-1,0,511))
                   - ga_eval(mt, mo, pyr, img, yi, clampi(xi+1,0,511))) * 0.5f;
        float g0 = -gyp * pl;                  // x component
        float g1 = -gxp * pl;                  // y component
        s0 = 0.99f * s0 + 0.01f * g0 * g0;
        s1 = 0.99f * s1 + 0.01f * g1 * g1;
        px = px - 0.2f * g0 / (sqrtf(s0) + 1e-8f);
        py = py - 0.2f * g1 / (sqrtf(s1) + 1e-8f);
    }
    pfin[2*i] = px; pfin[2*i+1] = py;
}

// ---- final: truncation fixup (rare) + masks_opt scatter + p_opt write ----
__global__ __launch_bounds__(256) void k_final(const float* __restrict__ pts,
                                               const float* __restrict__ mt,
                                               const float* __restrict__ mo,
                                               const float* __restrict__ pyr,
                                               const float* __restrict__ pfin,
                                               const float* __restrict__ plmax,
                                               float* __restrict__ mopt,
                                               float* __restrict__ pout) {
    int tstop = 10;
    #pragma unroll
    for (int t = 9; t >= 0; --t)
        if (!(plmax[t] > 0.1f)) tstop = t;
    int i = blockIdx.x * 256 + threadIdx.x;
    float px, py;
    if (tstop == 10) {                         // speculation exact (normal path)
        px = pfin[2*i]; py = pfin[2*i+1];
    } else {                                   // replay truncated trajectory
        px = pts[2*i]; py = pts[2*i+1];
        int img = i >> 7, n = i & 127;
        const float* M = mt + (size_t)img * HW;
        float d = expf(-(float)n * 0.078125f);
        float s0 = 0.0f, s1 = 0.0f;
        for (int t = 0; t < tstop; ++t) {
            int xi = clampi((int)rintf(px), 0, 511);
            int yi = clampi((int)rintf(py), 0, 511);
            float pl = (1.0f - M[yi*512 + xi]) * d;
            float gxp = (ga_eval(mt, mo, pyr, img, clampi(yi-1,0,511), xi)
                       - ga_eval(mt, mo, pyr, img, clampi(yi+1,0,511), xi)) * 0.5f;
            float gyp = (ga_eval(mt, mo, pyr, img, yi, clampi(xi-1,0,511))
                       - ga_eval(mt, mo, pyr, img, yi, clampi(xi+1,0,511))) * 0.5f;
            float g0 = -gyp * pl;
            float g1 = -gxp * pl;
            s0 = 0.99f * s0 + 0.01f * g0 * g0;
            s1 = 0.99f * s1 + 0.01f * g1 * g1;
            px = px - 0.2f * g0 / (sqrtf(s0) + 1e-8f);
            py = py - 0.2f * g1 / (sqrtf(s1) + 1e-8f);
        }
    }
    pout[2*i] = px; pout[2*i+1] = py;
    int xi = clampi((int)rintf(px), 0, 511);
    int yi = clampi((int)rintf(py), 0, 511);
    mopt[(i >> 7) * HW + yi*512 + xi] = 1.0f;
}

extern "C" void kernel_launch(void* const* d_in, const int* in_sizes, int n_in,
                              void* d_out, int out_size, void* d_ws, size_t ws_size,
                              hipStream_t stream) {
    const float* pts = (const float*)d_in[0];
    const float* mt  = (const float*)d_in[1];
    if (in_sizes[0] != NPTS * 2) { const float* tmp = pts; pts = mt; mt = tmp; }

    float* out  = (float*)d_out;
    float* mo   = out;                          // masks_out
    float* mopt = out + (size_t)IMGS * HW;      // masks_opt
    float* pout = out + 2 * (size_t)IMGS * HW;  // p_opt

    float* ws    = (float*)d_ws;
    float* pyr   = ws + PYR_OFF;
    float* pfin  = ws + PFIN_OFF;
    float* plmax = ws + PLMAX_OFF;
    int*   cnt   = (int*)(ws + CNT_OFF);
    int*   plist = (int*)(ws + LIST_OFF);

    // zero entire output (masks_out + masks_opt zeros; p_opt overwritten later)
    hipMemsetAsync(out, 0, (size_t)out_size * sizeof(float), stream);
    hipMemsetAsync(plmax, 0, 12 * sizeof(float), stream);   // plmax[0..10] + cnt

    k_scatter<<<NPTS/256, 256, 0, stream>>>(pts, mo, cnt, plist);
    k_lvl1<<<IMGS*65536/256, 256, 0, stream>>>(mt, pyr);
    k_corr1<<<NPTS/256, 256, 0, stream>>>(cnt, plist, pyr);
    k_lvl2<<<IMGS*16384/256, 256, 0, stream>>>(pyr, pyr + 6291456);
    k_pyrtail<<<IMGS, 256, 0, stream>>>(pyr);
    k_traj<<<NPTS/256, 256, 0, stream>>>(pts, mt, mo, pyr, pfin, plmax);
    k_final<<<NPTS/256, 256, 0, stream>>>(pts, mt, mo, pyr, pfin, plmax, mopt, pout);
}

// Round 9
// 420.427 us; speedup vs baseline: 1.0513x; 1.0513x over previous
//
#include <hip/hip_runtime.h>

#define IMGS 96
#define HW   262144      // 512*512
#define NPTS 12288       // 96*128
#define OOBV 1e-5f

// ws layout (float offsets)
static constexpr size_t PYR_OFF   = 0;        // 8,388,576 floats (levels 1..9, packed)
static constexpr size_t PFIN_OFF  = 8388576;  // 24576 floats (final p)
static constexpr size_t PLMAX_OFF = 8413152;  // 11 floats (plmax[0..10])
static constexpr size_t CNT_OFF   = 8413163;  // 1 int
static constexpr size_t LIST_OFF  = 8413164;  // 12288 ints

__device__ __forceinline__ int clampi(int v, int lo, int hi) {
    v = v < lo ? lo : v;
    return v > hi ? hi : v;
}

// ---- masks_out scatter + dedup'd owner list of set pixels ----
__global__ void k_scatter(const float* __restrict__ pts, float* __restrict__ mo,
                          int* __restrict__ cnt, int* __restrict__ plist) {
    int i = blockIdx.x * blockDim.x + threadIdx.x;
    if (i >= NPTS) return;
    float px = pts[2*i], py = pts[2*i+1];
    int xi = clampi((int)rintf(px), 0, 511);
    int yi = clampi((int)rintf(py), 0, 511);
    int gp = (i >> 7) * HW + yi * 512 + xi;
    float old = atomicExch(&mo[gp], 1.0f);
    if (old == 0.0f) {                 // first claimer owns this pixel
        int k = atomicAdd(cnt, 1);
        plist[k] = gp;
    }
}

// ---- level 1 (256^2) from -masks_target only (0.01*mo added as correction) ----
__global__ void k_lvl1(const float* __restrict__ mt, float* __restrict__ out) {
    int t = blockIdx.x * blockDim.x + threadIdx.x;
    if (t >= IMGS * 65536) return;
    int j = t & 255, i = (t >> 8) & 255, img = t >> 16;
    const float* m = mt + (size_t)img * HW;
    float s = 0.0f;
    #pragma unroll
    for (int dy = -1; dy <= 1; ++dy) {
        int y = 2*i + dy;
        #pragma unroll
        for (int dx = -1; dx <= 1; ++dx) {
            int x = 2*j + dx;
            s += (y >= 0 && y < 512 && x >= 0 && x < 512) ? -m[y*512 + x] : OOBV;
        }
    }
    out[t] = s / 9.0f;
}

// ---- sparse correction: each set pixel adds 0.01/9 to covering lvl1 cells ----
__global__ void k_corr1(const int* __restrict__ cnt, const int* __restrict__ plist,
                        float* __restrict__ lvl1) {
    int k = blockIdx.x * blockDim.x + threadIdx.x;
    if (k >= *cnt) return;
    int gp = plist[k];
    int img = gp >> 18;
    int r = gp & (HW - 1);
    int y = r >> 9, x = r & 511;
    float* L = lvl1 + (size_t)img * 65536;
    const float c = 0.01f / 9.0f;
    int ilo = y >> 1, ihi = ((y + 1) >> 1) > 255 ? 255 : ((y + 1) >> 1);
    int jlo = x >> 1, jhi = ((x + 1) >> 1) > 255 ? 255 : ((x + 1) >> 1);
    for (int i = ilo; i <= ihi; ++i)
        for (int j = jlo; j <= jhi; ++j)
            atomicAdd(&L[i*256 + j], c);
}

// ---- level 2 (128^2) from level 1 (256^2) ----
__global__ void k_lvl2(const float* __restrict__ in, float* __restrict__ out) {
    int t = blockIdx.x * blockDim.x + threadIdx.x;
    if (t >= IMGS * 16384) return;
    int j = t & 127, i = (t >> 7) & 127, img = t >> 14;
    const float* m = in + (size_t)img * 65536;
    float s = 0.0f;
    #pragma unroll
    for (int dy = -1; dy <= 1; ++dy) {
        int y = 2*i + dy;
        #pragma unroll
        for (int dx = -1; dx <= 1; ++dx) {
            int x = 2*j + dx;
            s += (y >= 0 && y < 256 && x >= 0 && x < 256) ? m[y*256 + x] : OOBV;
        }
    }
    out[t] = s / 9.0f;
}

// ---- levels 3..9 fused, one block per image, LDS resident ----
__global__ __launch_bounds__(256) void k_pyrtail(float* __restrict__ pyr) {
    __shared__ float buf[5461];   // 64^2 + 32^2 + 16^2 + 8^2 + 4^2 + 2^2 + 1
    int img = blockIdx.x;
    const float* L2 = pyr + 6291456 + (size_t)img * 16384;   // lvl2
    // level 3 (64^2) from global lvl2 (128^2)
    for (int t = threadIdx.x; t < 4096; t += 256) {
        int i = t >> 6, j = t & 63;
        float s = 0.0f;
        #pragma unroll
        for (int dy = -1; dy <= 1; ++dy) {
            int y = 2*i + dy;
            #pragma unroll
            for (int dx = -1; dx <= 1; ++dx) {
                int x = 2*j + dx;
                s += (y >= 0 && y < 128 && x >= 0 && x < 128) ? L2[y*128 + x] : OOBV;
            }
        }
        float v = s / 9.0f;
        buf[t] = v;
        pyr[7864320 + (size_t)img * 4096 + t] = v;
    }
    __syncthreads();
    // levels 4..9 from LDS
    int inOff = 0, sin = 64;
    size_t goff = 8257536;
    while (sin > 1) {
        int sout = sin >> 1;
        int outOff = inOff + sin * sin;
        for (int t = threadIdx.x; t < sout * sout; t += 256) {
            int i = t / sout, j = t - i * sout;
            float s = 0.0f;
            for (int dy = -1; dy <= 1; ++dy) {
                int y = 2*i + dy;
                for (int dx = -1; dx <= 1; ++dx) {
                    int x = 2*j + dx;
                    s += (y >= 0 && y < sin && x >= 0 && x < sin) ? buf[inOff + y*sin + x] : OOBV;
                }
            }
            float v = s / 9.0f;
            buf[outOff + t] = v;
            pyr[goff + (size_t)img * sout * sout + t] = v;
        }
        __syncthreads();
        inOff = outOff; sin = sout;
        goff += (size_t)96 * sout * sout;
    }
}

// ---- on-the-fly ga at one pixel: bit-identical to the old dense k_ga ----
__device__ __forceinline__ float ga_eval(const float* __restrict__ mt,
                                         const float* __restrict__ mo,
                                         const float* __restrict__ pyr,
                                         int img, int y, int x) {
    int idx = img * HW + y * 512 + x;
    float acc = -mt[idx];                      // grad0
    #pragma unroll
    for (int l = 0; l < 9; ++l) {
        const int s = 256 >> l;
        const float scale = (float)s * (1.0f / 512.0f);
        const float* Lp = pyr + (8388608 - (8388608 >> (2*l))) + (size_t)img * s * s;
        float fy = ((float)y + 0.5f) * scale - 0.5f;
        fy = fminf(fmaxf(fy, 0.0f), (float)(s - 1));   // edge clamp
        float fyf = floorf(fy);
        int y0 = (int)fyf;
        float ty = fy - fyf;
        int yb = (y0 + 1 < s) ? y0 + 1 : s - 1;
        float fx = ((float)x + 0.5f) * scale - 0.5f;
        fx = fminf(fmaxf(fx, 0.0f), (float)(s - 1));
        float fxf = floorf(fx);
        int x0 = (int)fxf;
        float tx = fx - fxf;
        int xb = (x0 + 1 < s) ? x0 + 1 : s - 1;        // pad-dup of last col
        float a = (1.0f - ty) * Lp[y0*s + x0] + ty * Lp[yb*s + x0];
        float b = (1.0f - ty) * Lp[y0*s + xb] + ty * Lp[yb*s + xb];
        acc += (1.0f - tx) * a + tx * b;
    }
    float v = acc / 10.0f;
    if (mo[idx] == 1.0f) v += 0.001f;          // dedup'd sparse correction
    return v;
}

// ---- speculative trajectory, 4 LANES PER POINT (occupancy fix for R8) ----
// Lane e of a point's 4-lane group computes eval e; a 2-shfl butterfly +
// lane-selects give every lane all four values; step math runs redundantly
// (identical FP sequence in all 4 lanes => stays synchronized, bit-exact).
__global__ __launch_bounds__(256) void k_traj(const float* __restrict__ pts,
                                              const float* __restrict__ mt,
                                              const float* __restrict__ mo,
                                              const float* __restrict__ pyr,
                                              float* __restrict__ pfin,
                                              float* __restrict__ plmax) {
    int g = blockIdx.x * 256 + threadIdx.x;    // grid exactly 192x256 = 4*NPTS
    int i = g >> 2;                            // point id
    int lane = threadIdx.x & 3;                // eval slot
    float px = pts[2*i], py = pts[2*i+1];
    int img = i >> 7, n = (i & 127);
    const float* M = mt + (size_t)img * HW;
    float d = expf(-(float)n * 0.078125f);     // exp(-n/128*10)
    float s0 = 0.0f, s1 = 0.0f;

    for (int t = 0; t < 10; ++t) {
        int xi = clampi((int)rintf(px), 0, 511);
        int yi = clampi((int)rintf(py), 0, 511);
        float pl = (1.0f - M[yi*512 + xi]) * d;
        // wave-level max (4 dup lanes per point don't change the max)
        float r = pl;
        #pragma unroll
        for (int off = 32; off; off >>= 1) r = fmaxf(r, __shfl_xor(r, off, 64));
        if ((threadIdx.x & 63) == 0)
            atomicMax((int*)&plmax[t], __float_as_int(r));  // pl>=0 => bit order ok
        // lane-selected eval coordinates (uniform control flow, no divergence)
        int ey = lane == 0 ? clampi(yi-1,0,511) : lane == 1 ? clampi(yi+1,0,511) : yi;
        int ex = lane == 2 ? clampi(xi-1,0,511) : lane == 3 ? clampi(xi+1,0,511) : xi;
        float v  = ga_eval(mt, mo, pyr, img, ey, ex);
        // butterfly: v=val[lane], v1=val[lane^1], v2=val[lane^2], v3=val[lane^3]
        float v1 = __shfl_xor(v, 1, 64);
        float v2 = __shfl_xor(v, 2, 64);
        float v3 = __shfl_xor(v1, 2, 64);
        float gym = lane==0 ? v : lane==1 ? v1 : lane==2 ? v2 : v3;   // eval@y-1
        float gyp_ = lane==1 ? v : lane==0 ? v1 : lane==3 ? v2 : v3;  // eval@y+1
        float gxm = lane==2 ? v : lane==3 ? v1 : lane==0 ? v2 : v3;   // eval@x-1
        float gxp_ = lane==3 ? v : lane==2 ? v1 : lane==1 ? v2 : v3;  // eval@x+1
        float gxp = (gym - gyp_) * 0.5f;       // d/dy central diff (ref's gx)
        float gyp = (gxm - gxp_) * 0.5f;       // d/dx central diff (ref's gy)
        float g0 = -gyp * pl;                  // x component
        float g1 = -gxp * pl;                  // y component
        s0 = 0.99f * s0 + 0.01f * g0 * g0;
        s1 = 0.99f * s1 + 0.01f * g1 * g1;
        px = px - 0.2f * g0 / (sqrtf(s0) + 1e-8f);
        py = py - 0.2f * g1 / (sqrtf(s1) + 1e-8f);
    }
    if (lane == 0) { pfin[2*i] = px; pfin[2*i+1] = py; }
}

// ---- final: truncation fixup (rare) + masks_opt scatter + p_opt write ----
__global__ __launch_bounds__(256) void k_final(const float* __restrict__ pts,
                                               const float* __restrict__ mt,
                                               const float* __restrict__ mo,
                                               const float* __restrict__ pyr,
                                               const float* __restrict__ pfin,
                                               const float* __restrict__ plmax,
                                               float* __restrict__ mopt,
                                               float* __restrict__ pout) {
    int tstop = 10;
    #pragma unroll
    for (int t = 9; t >= 0; --t)
        if (!(plmax[t] > 0.1f)) tstop = t;
    int i = blockIdx.x * 256 + threadIdx.x;
    float px, py;
    if (tstop == 10) {                         // speculation exact (normal path)
        px = pfin[2*i]; py = pfin[2*i+1];
    } else {                                   // replay truncated trajectory
        px = pts[2*i]; py = pts[2*i+1];
        int img = i >> 7, n = i & 127;
        const float* M = mt + (size_t)img * HW;
        float d = expf(-(float)n * 0.078125f);
        float s0 = 0.0f, s1 = 0.0f;
        for (int t = 0; t < tstop; ++t) {
            int xi = clampi((int)rintf(px), 0, 511);
            int yi = clampi((int)rintf(py), 0, 511);
            float pl = (1.0f - M[yi*512 + xi]) * d;
            float gxp = (ga_eval(mt, mo, pyr, img, clampi(yi-1,0,511), xi)
                       - ga_eval(mt, mo, pyr, img, clampi(yi+1,0,511), xi)) * 0.5f;
            float gyp = (ga_eval(mt, mo, pyr, img, yi, clampi(xi-1,0,511))
                       - ga_eval(mt, mo, pyr, img, yi, clampi(xi+1,0,511))) * 0.5f;
            float g0 = -gyp * pl;
            float g1 = -gxp * pl;
            s0 = 0.99f * s0 + 0.01f * g0 * g0;
            s1 = 0.99f * s1 + 0.01f * g1 * g1;
            px = px - 0.2f * g0 / (sqrtf(s0) + 1e-8f);
            py = py - 0.2f * g1 / (sqrtf(s1) + 1e-8f);
        }
    }
    pout[2*i] = px; pout[2*i+1] = py;
    int xi = clampi((int)rintf(px), 0, 511);
    int yi = clampi((int)rintf(py), 0, 511);
    mopt[(i >> 7) * HW + yi*512 + xi] = 1.0f;
}

extern "C" void kernel_launch(void* const* d_in, const int* in_sizes, int n_in,
                              void* d_out, int out_size, void* d_ws, size_t ws_size,
                              hipStream_t stream) {
    const float* pts = (const float*)d_in[0];
    const float* mt  = (const float*)d_in[1];
    if (in_sizes[0] != NPTS * 2) { const float* tmp = pts; pts = mt; mt = tmp; }

    float* out  = (float*)d_out;
    float* mo   = out;                          // masks_out
    float* mopt = out + (size_t)IMGS * HW;      // masks_opt
    float* pout = out + 2 * (size_t)IMGS * HW;  // p_opt

    float* ws    = (float*)d_ws;
    float* pyr   = ws + PYR_OFF;
    float* pfin  = ws + PFIN_OFF;
    float* plmax = ws + PLMAX_OFF;
    int*   cnt   = (int*)(ws + CNT_OFF);
    int*   plist = (int*)(ws + LIST_OFF);

    // zero entire output (masks_out + masks_opt zeros; p_opt overwritten later)
    hipMemsetAsync(out, 0, (size_t)out_size * sizeof(float), stream);
    hipMemsetAsync(plmax, 0, 12 * sizeof(float), stream);   // plmax[0..10] + cnt

    k_scatter<<<NPTS/256, 256, 0, stream>>>(pts, mo, cnt, plist);
    k_lvl1<<<IMGS*65536/256, 256, 0, stream>>>(mt, pyr);
    k_corr1<<<NPTS/256, 256, 0, stream>>>(cnt, plist, pyr);
    k_lvl2<<<IMGS*16384/256, 256, 0, stream>>>(pyr, pyr + 6291456);
    k_pyrtail<<<IMGS, 256, 0, stream>>>(pyr);
    k_traj<<<NPTS*4/256, 256, 0, stream>>>(pts, mt, mo, pyr, pfin, plmax);
    k_final<<<NPTS/256, 256, 0, stream>>>(pts, mt, mo, pyr, pfin, plmax, mopt, pout);
}